// Round 9
// baseline (228.958 us; speedup 1.0000x reference)
//
#include <hip/hip_runtime.h>
#include <math.h>

#define N_NODES   16000
#define N_EDGES   512000
#define EMBED_DIM 28
#define NODE_DIM  128
#define NUM_BASIS 20

#define EPB   128                   // edges per block
#define NBLK  (N_EDGES / EPB)       // 4000 edge blocks, exact

// node work: 16000*128 = 2.048M elems; 2000 blocks x 8 chunks x 128 threads
#define NODE_BLOCKS 2000
#define NODE_CHUNKS 8

// LDS pattern table: 9 patterns, pattern j at dword offset j*PSTRIDE + e*4.
// PSTRIDE = 516 dwords (128 f4 + 16B skew).
#define PSTRIDE 516
#define PAT_DWORDS (8 * PSTRIDE + EPB * 4)   // 4640 dwords = 18.56 KB

typedef float f32x4 __attribute__((ext_vector_type(4)));

// ---------------------------------------------------------------------------
// One kernel. Blocks < NBLK: edge work. Blocks >= NBLK: x_scalar.
// ---------------------------------------------------------------------------
__global__ __launch_bounds__(128) void fused_all_kernel(
    const int*   __restrict__ at_no,
    const float* __restrict__ pos,
    const int*   __restrict__ eidx,
    const float* __restrict__ embed,
    const float* __restrict__ W,
    const float* __restrict__ bias,
    float*       __restrict__ x_scalar,
    float*       __restrict__ rbf,
    float*       __restrict__ fcut,
    float*       __restrict__ rsh)
{
    const int t = threadIdx.x;

    if (blockIdx.x >= NBLK) {
        // ---- node branch: x_scalar = embed[at_no] @ W.T + b ----
        int bid2 = blockIdx.x - NBLK;
#pragma unroll 1
        for (int ch = 0; ch < NODE_CHUNKS; ++ch) {
            int idx  = (bid2 * NODE_CHUNKS + ch) * 128 + t;
            int node = idx >> 7;
            int d    = idx & 127;
            int a    = at_no[node];
            const float* er = embed + a * EMBED_DIM;
            const float* wr = W + d * EMBED_DIM;
            float sum = bias[d];
#pragma unroll
            for (int k = 0; k < EMBED_DIM; ++k)
                sum = fmaf(er[k], wr[k], sum);
            x_scalar[idx] = sum;
        }
        return;
    }

    __shared__ float sh_pat[PAT_DWORDS];    // 18.56 KB

    const int e0 = blockIdx.x * EPB;
    const int e  = e0 + t;

    // ---- Phase 1: edge compute ----
    {
        int s  = eidx[e];
        int dn = eidx[N_EDGES + e];

        // reference permutes pos columns by [1,2,0]
        float ax = pos[s*3+1],  ay = pos[s*3+2],  az = pos[s*3+0];
        float bx = pos[dn*3+1], by = pos[dn*3+2], bz = pos[dn*3+0];
        float vx = ax - bx, vy = ay - by, vz = az - bz;
        float dist = sqrtf(vx*vx + vy*vy + vz*vz);
        float inv  = 1.0f / dist;
        float ux = vx*inv, uy = vy*inv, uz = vz*inv;

        const float S3  = 1.7320508075688772f;
        const float S5  = 2.2360679774997896f;
        const float S15 = 3.8729833462074170f;
        float s0 = S3 * ux, s1 = S3 * uy, s2 = S3 * uz;
        float t0 = S15 * ux * uz;
        float t1 = S15 * ux * uy;
        float t2 = S5  * (uy*uy - 0.5f*(ux*ux + uz*uz));
        float t3 = S15 * uy * uz;
        float t4 = 0.5f * S15 * (uz*uz - ux*ux);

        f32x4* pb = (f32x4*)(sh_pat) + t;        // pattern j at + j*PSTRIDE/4
#define PW(j, a_, b_, c_, d_) { f32x4 v_; v_.x=a_; v_.y=b_; v_.z=c_; v_.w=d_; \
                                pb[(j) * (PSTRIDE/4)] = v_; }
        PW(0, 1.0f, 1.0f, 1.0f, 1.0f)
        PW(1, s0, s1, s2, s0)
        PW(2, s1, s2, s0, s1)
        PW(3, s2, s0, s1, s2)
        PW(4, t0, t1, t2, t3)
        PW(5, t1, t2, t3, t4)
        PW(6, t2, t3, t4, t0)
        PW(7, t3, t4, t0, t1)
        PW(8, t4, t0, t1, t2)
#undef PW

        // cutoff poly p=5: 1 - 21u^5 + 35u^6 - 15u^7
        float u  = dist * 0.2f;
        float u2 = u*u, u5 = u2*u2*u;
        float f  = 1.0f + u5*(-21.0f + u*(35.0f - 15.0f*u));
        fcut[e] = (u < 1.0f) ? f : 0.0f;

        // rbf[n] = sqrt(2/5) * sin(n*pi*dist/5)/dist via Chebyshev recurrence
        float th = 0.62831853071795864769f * dist;   // pi/5 * dist
        float sn = __sinf(th), cs = __cosf(th);
        float twoc = 2.0f * cs;
        float kk = 0.6324555320336759f * inv;
        float sp = 0.0f, sc = sn;
        f32x4* rb = (f32x4*)(rbf + (size_t)e * NUM_BASIS);
#pragma unroll
        for (int q = 0; q < 5; ++q) {
            f32x4 v_;
            v_.x = kk * sc; { float nx = twoc*sc - sp; sp = sc; sc = nx; }
            v_.y = kk * sc; { float nx = twoc*sc - sp; sp = sc; sc = nx; }
            v_.z = kk * sc; { float nx = twoc*sc - sp; sp = sc; sc = nx; }
            v_.w = kk * sc; { float nx = twoc*sc - sp; sp = sc; sc = nx; }
            rb[q] = v_;
        }
    }
    __syncthreads();

    // ---- Phase 2: rsh stream ----
    // Global f4 slot (relative to block) g = (i*15 + k)*128 + t, i<8, k<15.
    // le = g/120, c = g%120. Selector sequence has period 15 in k
    // (15*128 = 16*120), le advances exactly +16 per outer iter.
    {
        int offs[15];
#pragma unroll
        for (int k = 0; k < 15; ++k) {
            int u  = k * 128 + t;        // < 1920
            int d  = u / 120;
            int c  = u - d * 120;
            int p;
            if (c < 32)      p = 0;
            else if (c < 80) p = 1 + (c - 32) % 3;
            else             p = 4 + (4 * (c - 80)) % 5;
            offs[k] = p * PSTRIDE + d * 4;
        }

        float* outb = rsh + (size_t)e0 * 480 + (size_t)t * 4;
        int base = 0;                    // += 64 dwords (16 edges) per outer

#pragma unroll 1
        for (int i = 0; i < 8; ++i) {
#pragma unroll
            for (int k = 0; k < 15; ++k) {
                f32x4 v = *(const f32x4*)(sh_pat + base + offs[k]);
                *(f32x4*)(outb + (size_t)k * 512) = v;   // 512 floats = 128 f4
            }
            base += 64;
            outb += 15 * 512;
        }
    }
}

extern "C" void kernel_launch(void* const* d_in, const int* in_sizes, int n_in,
                              void* d_out, int out_size, void* d_ws, size_t ws_size,
                              hipStream_t stream) {
    const int*   at_no = (const int*)  d_in[0];
    const float* pos   = (const float*)d_in[1];
    const int*   eidx  = (const int*)  d_in[2];
    const float* embed = (const float*)d_in[3];
    const float* W     = (const float*)d_in[4];
    const float* b     = (const float*)d_in[5];

    float* out      = (float*)d_out;
    float* x_scalar = out;                                   // 16000*128
    float* rbf      = x_scalar + (size_t)N_NODES * NODE_DIM; // 512000*20
    float* fcut     = rbf + (size_t)N_EDGES * NUM_BASIS;     // 512000
    float* rsh      = fcut + N_EDGES;                        // 512000*480

    fused_all_kernel<<<NBLK + NODE_BLOCKS, 128, 0, stream>>>(
        at_no, pos, eidx, embed, W, b, x_scalar, rbf, fcut, rsh);
}

// Round 10
// 207.626 us; speedup vs baseline: 1.1027x; 1.1027x over previous
//
#include <hip/hip_runtime.h>
#include <math.h>

#define N_NODES   16000
#define N_EDGES   512000
#define EMBED_DIM 28
#define NODE_DIM  128
#define NUM_BASIS 20

#define EPB   128                   // edges per block
#define NBLK  (N_EDGES / EPB)       // 4000 edge blocks, exact

// node work at the FRONT of the grid: 16000*128 = 2.048M elems
// 2000 blocks x 8 chunks x 128 threads
#define NODE_BLOCKS 2000
#define NODE_CHUNKS 8

// LDS pattern table: 9 patterns, pattern j at dword offset j*PSTRIDE + e*4.
// PSTRIDE = 516 dwords (128 f4 + 16B skew).
#define PSTRIDE 516
#define PAT_DWORDS (8 * PSTRIDE + EPB * 4)   // 4640 dwords = 18.56 KB

typedef float f32x4 __attribute__((ext_vector_type(4)));

// ---------------------------------------------------------------------------
// One kernel. Blocks < NODE_BLOCKS: x_scalar. Blocks >= NODE_BLOCKS: edges.
// ---------------------------------------------------------------------------
__global__ __launch_bounds__(128) void fused_all_kernel(
    const int*   __restrict__ at_no,
    const float* __restrict__ pos,
    const int*   __restrict__ eidx,
    const float* __restrict__ embed,
    const float* __restrict__ W,
    const float* __restrict__ bias,
    float*       __restrict__ x_scalar,
    float*       __restrict__ rbf,
    float*       __restrict__ fcut,
    float*       __restrict__ rsh)
{
    const int t = threadIdx.x;

    if (blockIdx.x < NODE_BLOCKS) {
        // ---- node branch: x_scalar = embed[at_no] @ W.T + b ----
        int bid2 = blockIdx.x;
#pragma unroll 1
        for (int ch = 0; ch < NODE_CHUNKS; ++ch) {
            int idx  = (bid2 * NODE_CHUNKS + ch) * 128 + t;
            int node = idx >> 7;
            int d    = idx & 127;
            int a    = at_no[node];
            const float* er = embed + a * EMBED_DIM;
            const float* wr = W + d * EMBED_DIM;
            float sum = bias[d];
#pragma unroll
            for (int k = 0; k < EMBED_DIM; ++k)
                sum = fmaf(er[k], wr[k], sum);
            x_scalar[idx] = sum;
        }
        return;
    }

    __shared__ float sh_pat[PAT_DWORDS];    // 18.56 KB
    __shared__ float sh_rbf[EPB * 20];      // 10 KB, edge-major

    const int e0 = (blockIdx.x - NODE_BLOCKS) * EPB;
    const int e  = e0 + t;

    // ---- Phase 1: edge compute ----
    {
        int s  = eidx[e];
        int dn = eidx[N_EDGES + e];

        // reference permutes pos columns by [1,2,0]
        float ax = pos[s*3+1],  ay = pos[s*3+2],  az = pos[s*3+0];
        float bx = pos[dn*3+1], by = pos[dn*3+2], bz = pos[dn*3+0];
        float vx = ax - bx, vy = ay - by, vz = az - bz;
        float dist = sqrtf(vx*vx + vy*vy + vz*vz);
        float inv  = 1.0f / dist;
        float ux = vx*inv, uy = vy*inv, uz = vz*inv;

        const float S3  = 1.7320508075688772f;
        const float S5  = 2.2360679774997896f;
        const float S15 = 3.8729833462074170f;
        float s0 = S3 * ux, s1 = S3 * uy, s2 = S3 * uz;
        float t0 = S15 * ux * uz;
        float t1 = S15 * ux * uy;
        float t2 = S5  * (uy*uy - 0.5f*(ux*ux + uz*uz));
        float t3 = S15 * uy * uz;
        float t4 = 0.5f * S15 * (uz*uz - ux*ux);

        f32x4* pb = (f32x4*)(sh_pat) + t;        // pattern j at + j*PSTRIDE/4
#define PW(j, a_, b_, c_, d_) { f32x4 v_; v_.x=a_; v_.y=b_; v_.z=c_; v_.w=d_; \
                                pb[(j) * (PSTRIDE/4)] = v_; }
        PW(0, 1.0f, 1.0f, 1.0f, 1.0f)
        PW(1, s0, s1, s2, s0)
        PW(2, s1, s2, s0, s1)
        PW(3, s2, s0, s1, s2)
        PW(4, t0, t1, t2, t3)
        PW(5, t1, t2, t3, t4)
        PW(6, t2, t3, t4, t0)
        PW(7, t3, t4, t0, t1)
        PW(8, t4, t0, t1, t2)
#undef PW

        // cutoff poly p=5: 1 - 21u^5 + 35u^6 - 15u^7
        float u  = dist * 0.2f;
        float u2 = u*u, u5 = u2*u2*u;
        float f  = 1.0f + u5*(-21.0f + u*(35.0f - 15.0f*u));
        fcut[e] = (u < 1.0f) ? f : 0.0f;

        // rbf[n] = sqrt(2/5) * sin(n*pi*dist/5)/dist via Chebyshev recurrence
        float th = 0.62831853071795864769f * dist;   // pi/5 * dist
        float sn = __sinf(th), cs = __cosf(th);
        float twoc = 2.0f * cs;
        float kk = 0.6324555320336759f * inv;
        float sp = 0.0f, sc = sn;
        float* rb = sh_rbf + t * 20;
#pragma unroll
        for (int q = 0; q < NUM_BASIS; ++q) {
            rb[q] = kk * sc;
            float nx = twoc*sc - sp; sp = sc; sc = nx;
        }
    }
    __syncthreads();

    // ---- Phase 2: coalesced rbf writeout (5 x 128 float4) ----
    {
        const f32x4* ls = (const f32x4*)sh_rbf;
        f32x4* go = (f32x4*)(rbf + (size_t)e0 * NUM_BASIS);
#pragma unroll
        for (int q = 0; q < 5; ++q)
            go[q * EPB + t] = ls[q * EPB + t];
    }

    // ---- Phase 3: rsh stream ----
    // Global f4 slot (relative to block) g = (i*15 + k)*128 + t, i<8, k<15.
    // Selector sequence has period 15 in k (15*128 = 16*120); le advances
    // exactly +16 per outer iteration.
    {
        int offs[15];
#pragma unroll
        for (int k = 0; k < 15; ++k) {
            int u  = k * 128 + t;        // < 1920
            int d  = u / 120;
            int c  = u - d * 120;
            int p;
            if (c < 32)      p = 0;
            else if (c < 80) p = 1 + (c - 32) % 3;
            else             p = 4 + (4 * (c - 80)) % 5;
            offs[k] = p * PSTRIDE + d * 4;
        }

        float* outb = rsh + (size_t)e0 * 480 + (size_t)t * 4;
        int base = 0;                    // += 64 dwords (16 edges) per outer

#pragma unroll 1
        for (int i = 0; i < 8; ++i) {
#pragma unroll
            for (int k = 0; k < 15; ++k) {
                f32x4 v = *(const f32x4*)(sh_pat + base + offs[k]);
                *(f32x4*)(outb + (size_t)k * 512) = v;   // 512 floats = 128 f4
            }
            base += 64;
            outb += 15 * 512;
        }
    }
}

extern "C" void kernel_launch(void* const* d_in, const int* in_sizes, int n_in,
                              void* d_out, int out_size, void* d_ws, size_t ws_size,
                              hipStream_t stream) {
    const int*   at_no = (const int*)  d_in[0];
    const float* pos   = (const float*)d_in[1];
    const int*   eidx  = (const int*)  d_in[2];
    const float* embed = (const float*)d_in[3];
    const float* W     = (const float*)d_in[4];
    const float* b     = (const float*)d_in[5];

    float* out      = (float*)d_out;
    float* x_scalar = out;                                   // 16000*128
    float* rbf      = x_scalar + (size_t)N_NODES * NODE_DIM; // 512000*20
    float* fcut     = rbf + (size_t)N_EDGES * NUM_BASIS;     // 512000
    float* rsh      = fcut + N_EDGES;                        // 512000*480

    fused_all_kernel<<<NODE_BLOCKS + NBLK, 128, 0, stream>>>(
        at_no, pos, eidx, embed, W, b, x_scalar, rbf, fcut, rsh);
}

// Round 11
// 204.163 us; speedup vs baseline: 1.1214x; 1.0170x over previous
//
#include <hip/hip_runtime.h>
#include <math.h>

#define N_NODES   16000
#define N_EDGES   512000
#define EMBED_DIM 28
#define NODE_DIM  128
#define NUM_BASIS 20

#define EPB    128                       // edges per chunk
#define CHUNKS 4                         // chunks per edge block
#define EBLK   (N_EDGES / (EPB * CHUNKS))  // 1000 edge blocks

// node work at grid FRONT: 16000*128 = 2.048M elems = 500 blocks x 32 x 128
#define NODE_BLOCKS 500
#define NODE_CHUNKS 32

// LDS pattern table: 9 patterns, pattern j at dword offset j*PSTRIDE + e*4.
// PSTRIDE = 516 dwords (128 f4 + 16B skew). Double-buffered.
#define PSTRIDE 516
#define PAT_DWORDS (8 * PSTRIDE + EPB * 4)   // 4640 dwords = 18.56 KB

typedef float f32x4 __attribute__((ext_vector_type(4)));

// ---------------------------------------------------------------------------
// One kernel. Blocks < NODE_BLOCKS: x_scalar. Rest: persistent edge blocks,
// 4 chunks each, double-buffered sh_pat + register prefetch of next chunk.
// ---------------------------------------------------------------------------
__global__ __launch_bounds__(128) void fused_all_kernel(
    const int*   __restrict__ at_no,
    const float* __restrict__ pos,
    const int*   __restrict__ eidx,
    const float* __restrict__ embed,
    const float* __restrict__ W,
    const float* __restrict__ bias,
    float*       __restrict__ x_scalar,
    float*       __restrict__ rbf,
    float*       __restrict__ fcut,
    float*       __restrict__ rsh)
{
    const int t = threadIdx.x;

    if (blockIdx.x < NODE_BLOCKS) {
        // ---- node branch: x_scalar = embed[at_no] @ W.T + b ----
        int bid2 = blockIdx.x;
#pragma unroll 1
        for (int ch = 0; ch < NODE_CHUNKS; ++ch) {
            int idx  = (bid2 * NODE_CHUNKS + ch) * 128 + t;
            int node = idx >> 7;
            int d    = idx & 127;
            int a    = at_no[node];
            const float* er = embed + a * EMBED_DIM;
            const float* wr = W + d * EMBED_DIM;
            float sum = bias[d];
#pragma unroll
            for (int k = 0; k < EMBED_DIM; ++k)
                sum = fmaf(er[k], wr[k], sum);
            x_scalar[idx] = sum;
        }
        return;
    }

    __shared__ float sh_pat[2][PAT_DWORDS];   // 37.1 KB
    __shared__ float sh_rbf[EPB * 20];        // 10 KB

    const int blk = blockIdx.x - NODE_BLOCKS;

    // Loop-invariant selector offsets. Per-chunk f4 slot g = (i*15+k)*128+t;
    // period 15 in k (15*128 = 16*120); le advances +16 per outer iter.
    int offs[15];
#pragma unroll
    for (int k = 0; k < 15; ++k) {
        int u  = k * 128 + t;        // < 1920
        int d  = u / 120;
        int c  = u - d * 120;
        int p;
        if (c < 32)      p = 0;
        else if (c < 80) p = 1 + (c - 32) % 3;
        else             p = 4 + (4 * (c - 80)) % 5;
        offs[k] = p * PSTRIDE + d * 4;
    }

    // ---- prefetch chunk 0 inputs ----
    int e = blk * (EPB * CHUNKS) + t;
    int s  = eidx[e];
    int dn = eidx[N_EDGES + e];
    float ax = pos[s*3+1],  ay = pos[s*3+2],  az = pos[s*3+0];
    float bx = pos[dn*3+1], by = pos[dn*3+2], bz = pos[dn*3+0];

#pragma unroll 1
    for (int c = 0; c < CHUNKS; ++c) {
        const int ecur = blk * (EPB * CHUNKS) + c * EPB + t;
        const int ebase = blk * (EPB * CHUNKS) + c * EPB;

        // ---- compute current chunk from prefetched registers ----
        {
            float vx = ax - bx, vy = ay - by, vz = az - bz;
            float dist = sqrtf(vx*vx + vy*vy + vz*vz);
            float inv  = 1.0f / dist;
            float ux = vx*inv, uy = vy*inv, uz = vz*inv;

            const float S3  = 1.7320508075688772f;
            const float S5  = 2.2360679774997896f;
            const float S15 = 3.8729833462074170f;
            float s0 = S3 * ux, s1 = S3 * uy, s2 = S3 * uz;
            float t0 = S15 * ux * uz;
            float t1 = S15 * ux * uy;
            float t2 = S5  * (uy*uy - 0.5f*(ux*ux + uz*uz));
            float t3 = S15 * uy * uz;
            float t4 = 0.5f * S15 * (uz*uz - ux*ux);

            f32x4* pb = (f32x4*)(&sh_pat[c & 1][0]) + t;
#define PW(j, a_, b_, c_, d_) { f32x4 v_; v_.x=a_; v_.y=b_; v_.z=c_; v_.w=d_; \
                                pb[(j) * (PSTRIDE/4)] = v_; }
            PW(0, 1.0f, 1.0f, 1.0f, 1.0f)
            PW(1, s0, s1, s2, s0)
            PW(2, s1, s2, s0, s1)
            PW(3, s2, s0, s1, s2)
            PW(4, t0, t1, t2, t3)
            PW(5, t1, t2, t3, t4)
            PW(6, t2, t3, t4, t0)
            PW(7, t3, t4, t0, t1)
            PW(8, t4, t0, t1, t2)
#undef PW

            // cutoff poly p=5: 1 - 21u^5 + 35u^6 - 15u^7
            float u  = dist * 0.2f;
            float u2 = u*u, u5 = u2*u2*u;
            float f  = 1.0f + u5*(-21.0f + u*(35.0f - 15.0f*u));
            fcut[ecur] = (u < 1.0f) ? f : 0.0f;

            // rbf via Chebyshev recurrence: sin(n*th), th = pi*dist/5
            float th = 0.62831853071795864769f * dist;
            float sn = __sinf(th), cs = __cosf(th);
            float twoc = 2.0f * cs;
            float kk = 0.6324555320336759f * inv;
            float sp = 0.0f, sc = sn;
            float* rb = sh_rbf + t * 20;
#pragma unroll
            for (int q = 0; q < NUM_BASIS; ++q) {
                rb[q] = kk * sc;
                float nx = twoc*sc - sp; sp = sc; sc = nx;
            }
        }

        // ---- prefetch next chunk (loads in flight during store loop) ----
        if (c + 1 < CHUNKS) {
            int en = ecur + EPB;
            s  = eidx[en];
            dn = eidx[N_EDGES + en];
            ax = pos[s*3+1];  ay = pos[s*3+2];  az = pos[s*3+0];
            bx = pos[dn*3+1]; by = pos[dn*3+2]; bz = pos[dn*3+0];
        }

        __syncthreads();   // staging of chunk c complete

        // ---- rbf writeout (coalesced, 5 x 128 f4) ----
        {
            const f32x4* ls = (const f32x4*)sh_rbf;
            f32x4* go = (f32x4*)(rbf + (size_t)ebase * NUM_BASIS);
#pragma unroll
            for (int q = 0; q < 5; ++q)
                go[q * EPB + t] = ls[q * EPB + t];
        }

        // ---- rsh store loop ----
        {
            const float* patb = &sh_pat[c & 1][0];
            float* outb = rsh + (size_t)ebase * 480 + (size_t)t * 4;
            int base = 0;
#pragma unroll 1
            for (int i = 0; i < 8; ++i) {
#pragma unroll
                for (int k = 0; k < 15; ++k) {
                    f32x4 v = *(const f32x4*)(patb + base + offs[k]);
                    *(f32x4*)(outb + (size_t)k * 512) = v;
                }
                base += 64;
                outb += 15 * 512;
            }
        }

        __syncthreads();   // reads of pat[c&1] + sh_rbf done before overwrite
    }
}

extern "C" void kernel_launch(void* const* d_in, const int* in_sizes, int n_in,
                              void* d_out, int out_size, void* d_ws, size_t ws_size,
                              hipStream_t stream) {
    const int*   at_no = (const int*)  d_in[0];
    const float* pos   = (const float*)d_in[1];
    const int*   eidx  = (const int*)  d_in[2];
    const float* embed = (const float*)d_in[3];
    const float* W     = (const float*)d_in[4];
    const float* b     = (const float*)d_in[5];

    float* out      = (float*)d_out;
    float* x_scalar = out;                                   // 16000*128
    float* rbf      = x_scalar + (size_t)N_NODES * NODE_DIM; // 512000*20
    float* fcut     = rbf + (size_t)N_EDGES * NUM_BASIS;     // 512000
    float* rsh      = fcut + N_EDGES;                        // 512000*480

    fused_all_kernel<<<NODE_BLOCKS + EBLK, 128, 0, stream>>>(
        at_no, pos, eidx, embed, W, b, x_scalar, rbf, fcut, rsh);
}

// Round 12
// 201.120 us; speedup vs baseline: 1.1384x; 1.0151x over previous
//
#include <hip/hip_runtime.h>
#include <math.h>

#define N_NODES   16000
#define N_EDGES   512000
#define EMBED_DIM 28
#define NODE_DIM  128
#define NUM_BASIS 20

#define EPB    128                         // edges per chunk
#define CHUNKS 4                           // chunks per edge block
#define EBLK   (N_EDGES / (EPB * CHUNKS))  // 1000 edge blocks

// node work at grid FRONT: 16000*128 = 2.048M elems = 500 blocks x 32 x 128
#define NODE_BLOCKS 500
#define NODE_CHUNKS 32

// LDS pattern table: 9 patterns, pattern j at dword offset j*PSTRIDE + e*4.
// PSTRIDE = 516 dwords (128 f4 + 16B skew). Double-buffered.
#define PSTRIDE 516
#define PAT_DWORDS (8 * PSTRIDE + EPB * 4)   // 4640 dwords = 18.56 KB

typedef float f32x4 __attribute__((ext_vector_type(4)));

// ---------------------------------------------------------------------------
// One kernel. Blocks < NODE_BLOCKS: x_scalar. Rest: edge blocks, 4 chunks,
// CHUNK-MAJOR edge mapping: block b, chunk c -> edges (c*EBLK + b)*EPB.
// Co-resident blocks write one dense stripe together (write locality test).
// ---------------------------------------------------------------------------
__global__ __launch_bounds__(128) void fused_all_kernel(
    const int*   __restrict__ at_no,
    const float* __restrict__ pos,
    const int*   __restrict__ eidx,
    const float* __restrict__ embed,
    const float* __restrict__ W,
    const float* __restrict__ bias,
    float*       __restrict__ x_scalar,
    float*       __restrict__ rbf,
    float*       __restrict__ fcut,
    float*       __restrict__ rsh)
{
    const int t = threadIdx.x;

    if (blockIdx.x < NODE_BLOCKS) {
        // ---- node branch: x_scalar = embed[at_no] @ W.T + b ----
        int bid2 = blockIdx.x;
#pragma unroll 1
        for (int ch = 0; ch < NODE_CHUNKS; ++ch) {
            int idx  = (bid2 * NODE_CHUNKS + ch) * 128 + t;
            int node = idx >> 7;
            int d    = idx & 127;
            int a    = at_no[node];
            const float* er = embed + a * EMBED_DIM;
            const float* wr = W + d * EMBED_DIM;
            float sum = bias[d];
#pragma unroll
            for (int k = 0; k < EMBED_DIM; ++k)
                sum = fmaf(er[k], wr[k], sum);
            x_scalar[idx] = sum;
        }
        return;
    }

    __shared__ float sh_pat[2][PAT_DWORDS];   // 37.1 KB
    __shared__ float sh_rbf[EPB * 20];        // 10 KB

    const int blk = blockIdx.x - NODE_BLOCKS;

    // Loop-invariant selector offsets. Per-chunk f4 slot g = (i*15+k)*128+t;
    // period 15 in k (15*128 = 16*120); le advances +16 per outer iter.
    int offs[15];
#pragma unroll
    for (int k = 0; k < 15; ++k) {
        int u  = k * 128 + t;        // < 1920
        int d  = u / 120;
        int c  = u - d * 120;
        int p;
        if (c < 32)      p = 0;
        else if (c < 80) p = 1 + (c - 32) % 3;
        else             p = 4 + (4 * (c - 80)) % 5;
        offs[k] = p * PSTRIDE + d * 4;
    }

    // ---- prefetch chunk 0 inputs (chunk-major: ebase = (c*EBLK+blk)*EPB) --
    int s, dn;
    float ax, ay, az, bx, by, bz;
    {
        int e = blk * EPB + t;               // c = 0
        s  = eidx[e];
        dn = eidx[N_EDGES + e];
        ax = pos[s*3+1];  ay = pos[s*3+2];  az = pos[s*3+0];
        bx = pos[dn*3+1]; by = pos[dn*3+2]; bz = pos[dn*3+0];
    }

#pragma unroll 1
    for (int c = 0; c < CHUNKS; ++c) {
        const int ebase = (c * EBLK + blk) * EPB;
        const int ecur  = ebase + t;

        // ---- compute current chunk from prefetched registers ----
        {
            float vx = ax - bx, vy = ay - by, vz = az - bz;
            float dist = sqrtf(vx*vx + vy*vy + vz*vz);
            float inv  = 1.0f / dist;
            float ux = vx*inv, uy = vy*inv, uz = vz*inv;

            const float S3  = 1.7320508075688772f;
            const float S5  = 2.2360679774997896f;
            const float S15 = 3.8729833462074170f;
            float s0 = S3 * ux, s1 = S3 * uy, s2 = S3 * uz;
            float t0 = S15 * ux * uz;
            float t1 = S15 * ux * uy;
            float t2 = S5  * (uy*uy - 0.5f*(ux*ux + uz*uz));
            float t3 = S15 * uy * uz;
            float t4 = 0.5f * S15 * (uz*uz - ux*ux);

            f32x4* pb = (f32x4*)(&sh_pat[c & 1][0]) + t;
#define PW(j, a_, b_, c_, d_) { f32x4 v_; v_.x=a_; v_.y=b_; v_.z=c_; v_.w=d_; \
                                pb[(j) * (PSTRIDE/4)] = v_; }
            PW(0, 1.0f, 1.0f, 1.0f, 1.0f)
            PW(1, s0, s1, s2, s0)
            PW(2, s1, s2, s0, s1)
            PW(3, s2, s0, s1, s2)
            PW(4, t0, t1, t2, t3)
            PW(5, t1, t2, t3, t4)
            PW(6, t2, t3, t4, t0)
            PW(7, t3, t4, t0, t1)
            PW(8, t4, t0, t1, t2)
#undef PW

            // cutoff poly p=5: 1 - 21u^5 + 35u^6 - 15u^7
            float u  = dist * 0.2f;
            float u2 = u*u, u5 = u2*u2*u;
            float f  = 1.0f + u5*(-21.0f + u*(35.0f - 15.0f*u));
            fcut[ecur] = (u < 1.0f) ? f : 0.0f;

            // rbf via Chebyshev recurrence: sin(n*th), th = pi*dist/5
            float th = 0.62831853071795864769f * dist;
            float sn = __sinf(th), cs = __cosf(th);
            float twoc = 2.0f * cs;
            float kk = 0.6324555320336759f * inv;
            float sp = 0.0f, sc = sn;
            float* rb = sh_rbf + t * 20;
#pragma unroll
            for (int q = 0; q < NUM_BASIS; ++q) {
                rb[q] = kk * sc;
                float nx = twoc*sc - sp; sp = sc; sc = nx;
            }
        }

        // ---- prefetch next chunk (loads in flight during store loop) ----
        if (c + 1 < CHUNKS) {
            int en = ((c + 1) * EBLK + blk) * EPB + t;
            s  = eidx[en];
            dn = eidx[N_EDGES + en];
            ax = pos[s*3+1];  ay = pos[s*3+2];  az = pos[s*3+0];
            bx = pos[dn*3+1]; by = pos[dn*3+2]; bz = pos[dn*3+0];
        }

        __syncthreads();   // staging of chunk c complete

        // ---- rbf writeout (coalesced, 5 x 128 f4) ----
        {
            const f32x4* ls = (const f32x4*)sh_rbf;
            f32x4* go = (f32x4*)(rbf + (size_t)ebase * NUM_BASIS);
#pragma unroll
            for (int q = 0; q < 5; ++q)
                go[q * EPB + t] = ls[q * EPB + t];
        }

        // ---- rsh store loop ----
        {
            const float* patb = &sh_pat[c & 1][0];
            float* outb = rsh + (size_t)ebase * 480 + (size_t)t * 4;
            int base = 0;
#pragma unroll 1
            for (int i = 0; i < 8; ++i) {
#pragma unroll
                for (int k = 0; k < 15; ++k) {
                    f32x4 v = *(const f32x4*)(patb + base + offs[k]);
                    *(f32x4*)(outb + (size_t)k * 512) = v;
                }
                base += 64;
                outb += 15 * 512;
            }
        }

        __syncthreads();   // reads of pat[c&1] + sh_rbf done before overwrite
    }
}

extern "C" void kernel_launch(void* const* d_in, const int* in_sizes, int n_in,
                              void* d_out, int out_size, void* d_ws, size_t ws_size,
                              hipStream_t stream) {
    const int*   at_no = (const int*)  d_in[0];
    const float* pos   = (const float*)d_in[1];
    const int*   eidx  = (const int*)  d_in[2];
    const float* embed = (const float*)d_in[3];
    const float* W     = (const float*)d_in[4];
    const float* b     = (const float*)d_in[5];

    float* out      = (float*)d_out;
    float* x_scalar = out;                                   // 16000*128
    float* rbf      = x_scalar + (size_t)N_NODES * NODE_DIM; // 512000*20
    float* fcut     = rbf + (size_t)N_EDGES * NUM_BASIS;     // 512000
    float* rsh      = fcut + N_EDGES;                        // 512000*480

    fused_all_kernel<<<NODE_BLOCKS + EBLK, 128, 0, stream>>>(
        at_no, pos, eidx, embed, W, b, x_scalar, rbf, fcut, rsh);
}

// Round 13
// 200.902 us; speedup vs baseline: 1.1396x; 1.0011x over previous
//
#include <hip/hip_runtime.h>
#include <math.h>

#define N_NODES   16000
#define N_EDGES   512000
#define EMBED_DIM 28
#define NODE_DIM  128
#define NUM_BASIS 20

#define EPB    128                         // edges per chunk
#define CHUNKS 4                           // chunks per edge block
#define EBLK   (N_EDGES / (EPB * CHUNKS))  // 1000 edge blocks

// node work at grid FRONT: 16000*128 = 2.048M elems = 500 blocks x 32 x 128
#define NODE_BLOCKS 500
#define NODE_CHUNKS 32

// LDS pattern table: 9 patterns, pattern j at dword offset j*PSTRIDE + e*4.
// PSTRIDE = 516 dwords (128 f4 + 16B skew). Double-buffered.
#define PSTRIDE 516
#define PAT_DWORDS (8 * PSTRIDE + EPB * 4)   // 4640 dwords = 18.56 KB

typedef float f32x4 __attribute__((ext_vector_type(4)));

// Raw barrier: LDS-ordering only. Global stores stay IN FLIGHT across it
// (unlike __syncthreads(), which drains vmcnt(0) -- the m97 stall).
#define LDS_BARRIER() do {                                    \
    __builtin_amdgcn_sched_barrier(0);                        \
    asm volatile("s_waitcnt lgkmcnt(0)" ::: "memory");        \
    __builtin_amdgcn_s_barrier();                             \
    __builtin_amdgcn_sched_barrier(0);                        \
} while (0)

// ---------------------------------------------------------------------------
// One kernel. Blocks < NODE_BLOCKS: x_scalar. Rest: edge blocks, 4 chunks,
// chunk-major edge mapping: block b, chunk c -> edges (c*EBLK + b)*EPB.
// ---------------------------------------------------------------------------
__global__ __launch_bounds__(128) void fused_all_kernel(
    const int*   __restrict__ at_no,
    const float* __restrict__ pos,
    const int*   __restrict__ eidx,
    const float* __restrict__ embed,
    const float* __restrict__ W,
    const float* __restrict__ bias,
    float*       __restrict__ x_scalar,
    float*       __restrict__ rbf,
    float*       __restrict__ fcut,
    float*       __restrict__ rsh)
{
    const int t = threadIdx.x;

    if (blockIdx.x < NODE_BLOCKS) {
        // ---- node branch: x_scalar = embed[at_no] @ W.T + b ----
        int bid2 = blockIdx.x;
#pragma unroll 1
        for (int ch = 0; ch < NODE_CHUNKS; ++ch) {
            int idx  = (bid2 * NODE_CHUNKS + ch) * 128 + t;
            int node = idx >> 7;
            int d    = idx & 127;
            int a    = at_no[node];
            const float* er = embed + a * EMBED_DIM;
            const float* wr = W + d * EMBED_DIM;
            float sum = bias[d];
#pragma unroll
            for (int k = 0; k < EMBED_DIM; ++k)
                sum = fmaf(er[k], wr[k], sum);
            x_scalar[idx] = sum;
        }
        return;
    }

    __shared__ float sh_pat[2][PAT_DWORDS];   // 37.1 KB
    __shared__ float sh_rbf[EPB * 20];        // 10 KB

    const int blk = blockIdx.x - NODE_BLOCKS;

    // Loop-invariant selector offsets. Per-chunk f4 slot g = (i*15+k)*128+t;
    // period 15 in k (15*128 = 16*120); le advances +16 per outer iter.
    int offs[15];
#pragma unroll
    for (int k = 0; k < 15; ++k) {
        int u  = k * 128 + t;        // < 1920
        int d  = u / 120;
        int c  = u - d * 120;
        int p;
        if (c < 32)      p = 0;
        else if (c < 80) p = 1 + (c - 32) % 3;
        else             p = 4 + (4 * (c - 80)) % 5;
        offs[k] = p * PSTRIDE + d * 4;
    }

    // ---- prefetch chunk 0 inputs (chunk-major: ebase = (c*EBLK+blk)*EPB) --
    int s, dn;
    float ax, ay, az, bx, by, bz;
    {
        int e = blk * EPB + t;               // c = 0
        s  = eidx[e];
        dn = eidx[N_EDGES + e];
        ax = pos[s*3+1];  ay = pos[s*3+2];  az = pos[s*3+0];
        bx = pos[dn*3+1]; by = pos[dn*3+2]; bz = pos[dn*3+0];
    }

#pragma unroll 1
    for (int c = 0; c < CHUNKS; ++c) {
        const int ebase = (c * EBLK + blk) * EPB;
        const int ecur  = ebase + t;

        // ---- compute current chunk from prefetched registers ----
        {
            float vx = ax - bx, vy = ay - by, vz = az - bz;
            float dist = sqrtf(vx*vx + vy*vy + vz*vz);
            float inv  = 1.0f / dist;
            float ux = vx*inv, uy = vy*inv, uz = vz*inv;

            const float S3  = 1.7320508075688772f;
            const float S5  = 2.2360679774997896f;
            const float S15 = 3.8729833462074170f;
            float s0 = S3 * ux, s1 = S3 * uy, s2 = S3 * uz;
            float t0 = S15 * ux * uz;
            float t1 = S15 * ux * uy;
            float t2 = S5  * (uy*uy - 0.5f*(ux*ux + uz*uz));
            float t3 = S15 * uy * uz;
            float t4 = 0.5f * S15 * (uz*uz - ux*ux);

            f32x4* pb = (f32x4*)(&sh_pat[c & 1][0]) + t;
#define PW(j, a_, b_, c_, d_) { f32x4 v_; v_.x=a_; v_.y=b_; v_.z=c_; v_.w=d_; \
                                pb[(j) * (PSTRIDE/4)] = v_; }
            PW(0, 1.0f, 1.0f, 1.0f, 1.0f)
            PW(1, s0, s1, s2, s0)
            PW(2, s1, s2, s0, s1)
            PW(3, s2, s0, s1, s2)
            PW(4, t0, t1, t2, t3)
            PW(5, t1, t2, t3, t4)
            PW(6, t2, t3, t4, t0)
            PW(7, t3, t4, t0, t1)
            PW(8, t4, t0, t1, t2)
#undef PW

            // cutoff poly p=5: 1 - 21u^5 + 35u^6 - 15u^7
            float u  = dist * 0.2f;
            float u2 = u*u, u5 = u2*u2*u;
            float f  = 1.0f + u5*(-21.0f + u*(35.0f - 15.0f*u));
            fcut[ecur] = (u < 1.0f) ? f : 0.0f;

            // rbf via Chebyshev recurrence: sin(n*th), th = pi*dist/5
            float th = 0.62831853071795864769f * dist;
            float sn = __sinf(th), cs = __cosf(th);
            float twoc = 2.0f * cs;
            float kk = 0.6324555320336759f * inv;
            float sp = 0.0f, sc = sn;
            float* rb = sh_rbf + t * 20;
#pragma unroll
            for (int q = 0; q < NUM_BASIS; ++q) {
                rb[q] = kk * sc;
                float nx = twoc*sc - sp; sp = sc; sc = nx;
            }
        }

        // ---- prefetch next chunk (loads in flight during store loop) ----
        if (c + 1 < CHUNKS) {
            int en = ((c + 1) * EBLK + blk) * EPB + t;
            s  = eidx[en];
            dn = eidx[N_EDGES + en];
            ax = pos[s*3+1];  ay = pos[s*3+2];  az = pos[s*3+0];
            bx = pos[dn*3+1]; by = pos[dn*3+2]; bz = pos[dn*3+0];
        }

        LDS_BARRIER();     // staging of chunk c visible; stores stay in flight

        // ---- rbf writeout (coalesced, 5 x 128 f4) ----
        {
            const f32x4* ls = (const f32x4*)sh_rbf;
            f32x4* go = (f32x4*)(rbf + (size_t)ebase * NUM_BASIS);
#pragma unroll
            for (int q = 0; q < 5; ++q)
                go[q * EPB + t] = ls[q * EPB + t];
        }

        // ---- rsh store loop ----
        {
            const float* patb = &sh_pat[c & 1][0];
            float* outb = rsh + (size_t)ebase * 480 + (size_t)t * 4;
            int base = 0;
#pragma unroll 1
            for (int i = 0; i < 8; ++i) {
#pragma unroll
                for (int k = 0; k < 15; ++k) {
                    f32x4 v = *(const f32x4*)(patb + base + offs[k]);
                    *(f32x4*)(outb + (size_t)k * 512) = v;
                }
                base += 64;
                outb += 15 * 512;
            }
        }

        LDS_BARRIER();     // ds_reads of pat[c&1]+sh_rbf done; no vmcnt drain
    }
}

extern "C" void kernel_launch(void* const* d_in, const int* in_sizes, int n_in,
                              void* d_out, int out_size, void* d_ws, size_t ws_size,
                              hipStream_t stream) {
    const int*   at_no = (const int*)  d_in[0];
    const float* pos   = (const float*)d_in[1];
    const int*   eidx  = (const int*)  d_in[2];
    const float* embed = (const float*)d_in[3];
    const float* W     = (const float*)d_in[4];
    const float* b     = (const float*)d_in[5];

    float* out      = (float*)d_out;
    float* x_scalar = out;                                   // 16000*128
    float* rbf      = x_scalar + (size_t)N_NODES * NODE_DIM; // 512000*20
    float* fcut     = rbf + (size_t)N_EDGES * NUM_BASIS;     // 512000
    float* rsh      = fcut + N_EDGES;                        // 512000*480

    fused_all_kernel<<<NODE_BLOCKS + EBLK, 128, 0, stream>>>(
        at_no, pos, eidx, embed, W, b, x_scalar, rbf, fcut, rsh);
}